// Round 2
// baseline (4031.050 us; speedup 1.0000x reference)
//
#include <hip/hip_runtime.h>
#include <stdint.h>
#include <math.h>

typedef unsigned short u16;
typedef short s16x8 __attribute__((ext_vector_type(8)));
typedef float f32x4 __attribute__((ext_vector_type(4)));

// ---- problem constants ----
#define BB 2
#define SS 2048
#define DIM 2048
#define NH 16
#define NOPE 128
#define ROPED 64
#define VH 128
#define KVR 512
#define NE 8
#define MINTER 1408
#define SHI 2816
#define TT 4096          // B*S
#define QD 192           // NOPE+ROPE

__device__ __forceinline__ u16 f2bf(float f) {
  unsigned u = __builtin_bit_cast(unsigned, f);
  u += 0x7fffu + ((u >> 16) & 1u);   // RNE
  return (u16)(u >> 16);
}
__device__ __forceinline__ float bf2f(u16 h) {
  return __builtin_bit_cast(float, ((unsigned)h) << 16);
}
__device__ __forceinline__ void split2(float v, u16& hi, u16& lo) {
  u16 h = f2bf(v);
  hi = h;
  lo = f2bf(v - bf2f(h));
}

// ---------------- converts ----------------
__global__ void split_f32(const float* __restrict__ in, u16* __restrict__ hi,
                          u16* __restrict__ lo, int n) {
  int i = blockIdx.x * 256 + threadIdx.x;
  if (i < n) split2(in[i], hi[i], lo[i]);
}
__global__ void cvt3_bf16(const float* __restrict__ a, const float* __restrict__ b,
                          const float* __restrict__ c, u16* __restrict__ oa,
                          u16* __restrict__ ob, u16* __restrict__ oc, int n) {
  int i = blockIdx.x * 256 + threadIdx.x;
  if (i < n) { oa[i] = f2bf(a[i]); ob[i] = f2bf(b[i]); oc[i] = f2bf(c[i]); }
}
// wkv_a (576x2048) -> padded 640x2048 split (zero rows 576..639)
__global__ void split_wkva(const float* __restrict__ in, u16* __restrict__ hi,
                           u16* __restrict__ lo) {
  int i = blockIdx.x * 256 + threadIdx.x;  // over 640*2048
  int row = i >> 11;
  float v = (row < 576) ? in[(size_t)row * 2048 + (i & 2047)] : 0.f;
  split2(v, hi[i], lo[i]);
}

// ---------------- rmsnorm (D=2048) f32 -> split bf16 pair ----------------
__global__ __launch_bounds__(256) void rmsnorm_split(const float* __restrict__ x,
                                                     const float* __restrict__ w,
                                                     u16* __restrict__ oh,
                                                     u16* __restrict__ ol) {
  int t = blockIdx.x;
  const float* xr = x + (size_t)t * DIM;
  float ss = 0.f;
#pragma unroll
  for (int i = 0; i < 8; i++) { float v = xr[threadIdx.x + i * 256]; ss += v * v; }
#pragma unroll
  for (int off = 32; off; off >>= 1) ss += __shfl_xor(ss, off, 64);
  __shared__ float red[4];
  if ((threadIdx.x & 63) == 0) red[threadIdx.x >> 6] = ss;
  __syncthreads();
  ss = red[0] + red[1] + red[2] + red[3];
  float rstd = rsqrtf(ss * (1.f / DIM) + 1e-6f);
#pragma unroll
  for (int i = 0; i < 8; i++) {
    int c = threadIdx.x + i * 256;
    float v = xr[c] * rstd * w[c];
    split2(v, oh[(size_t)t * DIM + c], ol[(size_t)t * DIM + c]);
  }
}

// ---------------- rmsnorm f32 -> bf16 (FFN input) ----------------
__global__ __launch_bounds__(256) void rmsnorm_bf16(const float* __restrict__ x,
                                                    const float* __restrict__ w,
                                                    u16* __restrict__ out) {
  int t = blockIdx.x;
  const float* xr = x + (size_t)t * DIM;
  float ss = 0.f;
#pragma unroll
  for (int i = 0; i < 8; i++) { float v = xr[threadIdx.x + i * 256]; ss += v * v; }
#pragma unroll
  for (int off = 32; off; off >>= 1) ss += __shfl_xor(ss, off, 64);
  __shared__ float red[4];
  if ((threadIdx.x & 63) == 0) red[threadIdx.x >> 6] = ss;
  __syncthreads();
  ss = red[0] + red[1] + red[2] + red[3];
  float rstd = rsqrtf(ss * (1.f / DIM) + 1e-6f);
#pragma unroll
  for (int i = 0; i < 8; i++) {
    int c = threadIdx.x + i * 256;
    out[(size_t)t * DIM + c] = f2bf(xr[c] * rstd * w[c]);
  }
}

// ---------------- kv: rmsnorm(512) + rope(k_pe), f32 in -> split outs ----------------
__global__ __launch_bounds__(256) void kv_norm_rope_split(const float* __restrict__ kv,
                                                          const float* __restrict__ w,
                                                          const float* __restrict__ fcos,
                                                          const float* __restrict__ fsin,
                                                          u16* __restrict__ ckvh,
                                                          u16* __restrict__ ckvl,
                                                          u16* __restrict__ peh,
                                                          u16* __restrict__ pel) {
  int t = blockIdx.x;
  int pos = t & (SS - 1);
  const float* kr = kv + (size_t)t * 640;
  float v0 = kr[threadIdx.x], v1 = kr[threadIdx.x + 256];
  float ss = v0 * v0 + v1 * v1;
#pragma unroll
  for (int off = 32; off; off >>= 1) ss += __shfl_xor(ss, off, 64);
  __shared__ float red[4];
  if ((threadIdx.x & 63) == 0) red[threadIdx.x >> 6] = ss;
  __syncthreads();
  ss = red[0] + red[1] + red[2] + red[3];
  float rstd = rsqrtf(ss * (1.f / KVR) + 1e-6f);
  float a0 = v0 * rstd * w[threadIdx.x];
  float a1 = v1 * rstd * w[threadIdx.x + 256];
  split2(a0, ckvh[(size_t)t * KVR + threadIdx.x], ckvl[(size_t)t * KVR + threadIdx.x]);
  split2(a1, ckvh[(size_t)t * KVR + threadIdx.x + 256], ckvl[(size_t)t * KVR + threadIdx.x + 256]);
  if (threadIdx.x < 32) {
    int i = threadIdx.x;
    float x1 = kr[KVR + 2 * i], x2 = kr[KVR + 2 * i + 1];
    float c = fcos[pos * 32 + i], s = fsin[pos * 32 + i];
    split2(x1 * c - x2 * s, peh[(size_t)t * 64 + 2 * i], pel[(size_t)t * 64 + 2 * i]);
    split2(x1 * s + x2 * c, peh[(size_t)t * 64 + 2 * i + 1], pel[(size_t)t * 64 + 2 * i + 1]);
  }
}

// ---------------- rope on q_pe slices (f32 q, in-place) ----------------
__global__ void rope_qf(float* __restrict__ q, const float* __restrict__ fcos,
                        const float* __restrict__ fsin) {
  int idx = blockIdx.x * 256 + threadIdx.x;  // TT*NH*32
  if (idx >= TT * NH * 32) return;
  int i = idx & 31;
  int rem = idx >> 5;
  int h = rem & 15, t = rem >> 4;
  int pos = t & (SS - 1);
  size_t base = (size_t)t * (NH * QD) + h * QD + NOPE + 2 * i;
  float x1 = q[base], x2 = q[base + 1];
  float c = fcos[pos * 32 + i], s = fsin[pos * 32 + i];
  q[base] = x1 * c - x2 * s;
  q[base + 1] = x1 * s + x2 * c;
}

// ---------------- residual: h += x; out = h ----------------
__global__ void add_residual(float* __restrict__ h, const float* __restrict__ x,
                             float* __restrict__ out, int n) {
  int i = blockIdx.x * 256 + threadIdx.x;
  if (i < n) {
    float v = h[i] + x[i];
    h[i] = v;
    out[i] = v;
  }
}

// ---------------- router, fully f32 from h (inline rmsnorm) ----------------
__global__ __launch_bounds__(256) void router_f32(const float* __restrict__ h,
                                                  const float* __restrict__ wn,
                                                  const float* __restrict__ rw,
                                                  float* __restrict__ gates) {
  int t = blockIdx.x;
  const float* xr = h + (size_t)t * DIM;
  float xv[8];
  float ss = 0.f;
#pragma unroll
  for (int i = 0; i < 8; i++) { xv[i] = xr[threadIdx.x + i * 256]; ss += xv[i] * xv[i]; }
#pragma unroll
  for (int off = 32; off; off >>= 1) ss += __shfl_xor(ss, off, 64);
  __shared__ float red4[4];
  if ((threadIdx.x & 63) == 0) red4[threadIdx.x >> 6] = ss;
  __syncthreads();
  ss = red4[0] + red4[1] + red4[2] + red4[3];
  float rstd = rsqrtf(ss * (1.f / DIM) + 1e-6f);
  float p[8];
#pragma unroll
  for (int e = 0; e < 8; e++) p[e] = 0.f;
#pragma unroll
  for (int i = 0; i < 8; i++) {
    int c = threadIdx.x + i * 256;
    float nv = xv[i] * rstd * wn[c];
#pragma unroll
    for (int e = 0; e < 8; e++) p[e] += nv * rw[e * DIM + c];
  }
  __shared__ float red[8 * 256];
#pragma unroll
  for (int e = 0; e < 8; e++) red[e * 256 + threadIdx.x] = p[e];
  __syncthreads();
  for (int st = 128; st > 0; st >>= 1) {
    if (threadIdx.x < st) {
#pragma unroll
      for (int e = 0; e < 8; e++) red[e * 256 + threadIdx.x] += red[e * 256 + threadIdx.x + st];
    }
    __syncthreads();
  }
  if (threadIdx.x == 0) {
    float lg[8], mx = -1e30f;
#pragma unroll
    for (int e = 0; e < 8; e++) { lg[e] = red[e * 256]; mx = fmaxf(mx, lg[e]); }
#pragma unroll
    for (int e = 0; e < 8; e++) lg[e] = expf(lg[e] - mx);
    int i1 = 0;
#pragma unroll
    for (int e = 1; e < 8; e++) if (lg[e] > lg[i1]) i1 = e;
    int i2 = -1;
#pragma unroll
    for (int e = 0; e < 8; e++) if (e != i1 && (i2 < 0 || lg[e] > lg[i2])) i2 = e;
    float v1 = lg[i1], v2 = lg[i2], vs = v1 + v2;
#pragma unroll
    for (int e = 0; e < 8; e++) gates[t * 8 + e] = 0.f;
    gates[t * 8 + i1] = v1 / vs;
    gates[t * 8 + i2] = v2 / vs;
  }
}

// ---------------- silu(g1)*g3, bf16 in/out ----------------
__global__ void silu_mul(const u16* __restrict__ g1, const u16* __restrict__ g3,
                         u16* __restrict__ out, int n) {
  int i = blockIdx.x * 256 + threadIdx.x;
  if (i < n) {
    float a = bf2f(g1[i]), c = bf2f(g3[i]);
    out[i] = f2bf(a / (1.f + expf(-a)) * c);
  }
}

// ---------------- GEMM: C[M,N] = A[M,K] @ W[N,K]^T, bf16 in, f32 acc ----------------
enum { EPI_BF16 = 0, EPI_F32 = 1, EPI_ADD = 3, EPI_ADD_GATED = 4 };

template <int EPI>
__global__ __launch_bounds__(256) void gemm_bt(const u16* __restrict__ A,
                                               const u16* __restrict__ W,
                                               void* __restrict__ C,
                                               const float* __restrict__ aux,
                                               int M, int N, int K) {
  __shared__ u16 As[128 * 40];
  __shared__ u16 Ws[128 * 40];
  int tid = threadIdx.x;
  int lane = tid & 63;
  int l16 = lane & 15, quad = lane >> 4;
  int wv = tid >> 6;
  int wrow = wv & 1, wcol = wv >> 1;
  int bm = blockIdx.y * 128, bn = blockIdx.x * 128;
  const u16* Ab = A + (size_t)bm * K;
  const u16* Wb = W + (size_t)bn * K;
  int srow = tid >> 2, scol = (tid & 3) * 8;

  f32x4 acc[4][4];
#pragma unroll
  for (int mt = 0; mt < 4; mt++)
#pragma unroll
    for (int nt = 0; nt < 4; nt++) acc[mt][nt] = (f32x4){0.f, 0.f, 0.f, 0.f};

  for (int k0 = 0; k0 < K; k0 += 32) {
    s16x8 a0 = *(const s16x8*)&Ab[(size_t)srow * K + k0 + scol];
    s16x8 a1 = *(const s16x8*)&Ab[(size_t)(srow + 64) * K + k0 + scol];
    s16x8 w0 = *(const s16x8*)&Wb[(size_t)srow * K + k0 + scol];
    s16x8 w1 = *(const s16x8*)&Wb[(size_t)(srow + 64) * K + k0 + scol];
    __syncthreads();
    *(s16x8*)&As[srow * 40 + scol] = a0;
    *(s16x8*)&As[(srow + 64) * 40 + scol] = a1;
    *(s16x8*)&Ws[srow * 40 + scol] = w0;
    *(s16x8*)&Ws[(srow + 64) * 40 + scol] = w1;
    __syncthreads();
    s16x8 af[4], wf[4];
#pragma unroll
    for (int mt = 0; mt < 4; mt++)
      af[mt] = *(const s16x8*)&As[(wrow * 64 + mt * 16 + l16) * 40 + quad * 8];
#pragma unroll
    for (int nt = 0; nt < 4; nt++)
      wf[nt] = *(const s16x8*)&Ws[(wcol * 64 + nt * 16 + l16) * 40 + quad * 8];
#pragma unroll
    for (int mt = 0; mt < 4; mt++)
#pragma unroll
      for (int nt = 0; nt < 4; nt++)
        acc[mt][nt] = __builtin_amdgcn_mfma_f32_16x16x32_bf16(af[mt], wf[nt], acc[mt][nt], 0, 0, 0);
  }
#pragma unroll
  for (int mt = 0; mt < 4; mt++) {
#pragma unroll
    for (int r = 0; r < 4; r++) {
      int row = bm + wrow * 64 + mt * 16 + quad * 4 + r;
#pragma unroll
      for (int nt = 0; nt < 4; nt++) {
        int col = bn + wcol * 64 + nt * 16 + l16;
        float v = acc[mt][nt][r];
        size_t idx = (size_t)row * N + col;
        if constexpr (EPI == EPI_BF16) ((u16*)C)[idx] = f2bf(v);
        else if constexpr (EPI == EPI_F32) ((float*)C)[idx] = v;
        else if constexpr (EPI == EPI_ADD) ((float*)C)[idx] += v;
        else ((float*)C)[idx] += aux[(size_t)row * 8] * v;  // gated accumulate
      }
    }
  }
}

// ---------------- flash attention, split-bf16 (causal, d_qk=192, d_v=128) ----------------
// grid (32 qtiles of 64, 32 b*h). 4 waves; wave w owns Q rows w*16..w*16+16.
// 32-key tiles; hi/lo staged; S = qh*kh + qh*kl + ql*kh; PV = Ph*Vh + Ph*Vl + Pl*Vh.
__global__ __launch_bounds__(256) void flash_attn_split(
    const u16* __restrict__ Qh, const u16* __restrict__ Ql,
    const u16* __restrict__ KVh, const u16* __restrict__ KVl,
    const u16* __restrict__ Peh, const u16* __restrict__ Pel,
    float* __restrict__ O) {
  __shared__ u16 Ksh[32 * 200], Ksl[32 * 200];
  __shared__ u16 Vth[128 * 40], Vtl[128 * 40];
  __shared__ u16 Psh[64 * 40], Psl[64 * 40];
  int tid = threadIdx.x;
  int lane = tid & 63, wv = tid >> 6;
  int l16 = lane & 15, quad = lane >> 4;
  int qt = blockIdx.x;
  int b = blockIdx.y >> 4, h = blockIdx.y & 15;
  int tb = b * SS;
  const float kSc = 0.07216878364870322f * 1.4426950408889634f;  // 1/sqrt(192)*log2(e)

  s16x8 qfh[6], qfl[6];
  {
    int qrow = tb + qt * 64 + wv * 16 + l16;
    const u16* ph = Qh + (size_t)qrow * (NH * QD) + h * QD;
    const u16* pl = Ql + (size_t)qrow * (NH * QD) + h * QD;
#pragma unroll
    for (int s = 0; s < 6; s++) {
      qfh[s] = *(const s16x8*)&ph[s * 32 + quad * 8];
      qfl[s] = *(const s16x8*)&pl[s * 32 + quad * 8];
    }
  }
  float m_i[4], l_i[4];
#pragma unroll
  for (int r = 0; r < 4; r++) { m_i[r] = -1e30f; l_i[r] = 0.f; }
  f32x4 o_acc[8];
#pragma unroll
  for (int nt = 0; nt < 8; nt++) o_acc[nt] = (f32x4){0.f, 0.f, 0.f, 0.f};

  int nkt = 2 * qt + 2;
  for (int kt = 0; kt < nkt; kt++) {
    __syncthreads();
    // stage K nope (32 rows x 128)
#pragma unroll
    for (int i = 0; i < 2; i++) {
      int c = tid + i * 256;
      int row = c >> 4, cc = (c & 15) * 8;
      size_t g = (size_t)(tb + kt * 32 + row) * 4096 + h * 256 + cc;
      *(s16x8*)&Ksh[row * 200 + cc] = *(const s16x8*)&KVh[g];
      *(s16x8*)&Ksl[row * 200 + cc] = *(const s16x8*)&KVl[g];
    }
    // stage K pe (32 rows x 64)
    {
      int row = tid >> 3, cc = (tid & 7) * 8;
      size_t g = (size_t)(tb + kt * 32 + row) * 64 + cc;
      *(s16x8*)&Ksh[row * 200 + 128 + cc] = *(const s16x8*)&Peh[g];
      *(s16x8*)&Ksl[row * 200 + 128 + cc] = *(const s16x8*)&Pel[g];
    }
    // stage Vt (transpose 32 keys x 128 vdim)
#pragma unroll
    for (int i = 0; i < 16; i++) {
      int idx = tid + i * 256;
      int n = idx & 127, k = idx >> 7;
      size_t g = (size_t)(tb + kt * 32 + k) * 4096 + h * 256 + 128 + n;
      Vth[n * 40 + k] = KVh[g];
      Vtl[n * 40 + k] = KVl[g];
    }
    __syncthreads();
    // scores: 2 col-tiles of 16 keys
    f32x4 sc[2];
#pragma unroll
    for (int ct = 0; ct < 2; ct++) {
      f32x4 a = (f32x4){0.f, 0.f, 0.f, 0.f};
#pragma unroll
      for (int s = 0; s < 6; s++) {
        s16x8 kh = *(const s16x8*)&Ksh[(ct * 16 + l16) * 200 + s * 32 + quad * 8];
        s16x8 kl = *(const s16x8*)&Ksl[(ct * 16 + l16) * 200 + s * 32 + quad * 8];
        a = __builtin_amdgcn_mfma_f32_16x16x32_bf16(qfh[s], kh, a, 0, 0, 0);
        a = __builtin_amdgcn_mfma_f32_16x16x32_bf16(qfh[s], kl, a, 0, 0, 0);
        a = __builtin_amdgcn_mfma_f32_16x16x32_bf16(qfl[s], kh, a, 0, 0, 0);
      }
      sc[ct] = a;
    }
    float rowmax[4];
#pragma unroll
    for (int r = 0; r < 4; r++) rowmax[r] = -1e30f;
#pragma unroll
    for (int ct = 0; ct < 2; ct++) {
#pragma unroll
      for (int r = 0; r < 4; r++) {
        float v = sc[ct][r] * kSc;  // log2-domain scaled score
        int kg = kt * 32 + ct * 16 + l16;
        int qg = qt * 64 + wv * 16 + quad * 4 + r;
        if (kg > qg) v = -1e30f;   // causal
        sc[ct][r] = v;
        rowmax[r] = fmaxf(rowmax[r], v);
      }
    }
#pragma unroll
    for (int r = 0; r < 4; r++) {
      float v = rowmax[r];
#pragma unroll
      for (int off = 1; off < 16; off <<= 1) v = fmaxf(v, __shfl_xor(v, off, 64));
      rowmax[r] = v;
    }
    float alpha[4], rs[4];
#pragma unroll
    for (int r = 0; r < 4; r++) {
      float mn = fmaxf(m_i[r], rowmax[r]);
      alpha[r] = exp2f(m_i[r] - mn);
      m_i[r] = mn;
      rs[r] = 0.f;
    }
#pragma unroll
    for (int ct = 0; ct < 2; ct++) {
#pragma unroll
      for (int r = 0; r < 4; r++) {
        float p = exp2f(sc[ct][r] - m_i[r]);
        rs[r] += p;
        int prow = (wv * 16 + quad * 4 + r) * 40 + ct * 16 + l16;
        u16 hb = f2bf(p);
        Psh[prow] = hb;
        Psl[prow] = f2bf(p - bf2f(hb));
      }
    }
#pragma unroll
    for (int r = 0; r < 4; r++) {
      float v = rs[r];
#pragma unroll
      for (int off = 1; off < 16; off <<= 1) v += __shfl_xor(v, off, 64);
      l_i[r] = l_i[r] * alpha[r] + v;
    }
#pragma unroll
    for (int nt = 0; nt < 8; nt++)
#pragma unroll
      for (int r = 0; r < 4; r++) o_acc[nt][r] *= alpha[r];
    __syncthreads();
    s16x8 pfh = *(const s16x8*)&Psh[(wv * 16 + l16) * 40 + quad * 8];
    s16x8 pfl = *(const s16x8*)&Psl[(wv * 16 + l16) * 40 + quad * 8];
#pragma unroll
    for (int nt = 0; nt < 8; nt++) {
      s16x8 vh = *(const s16x8*)&Vth[(nt * 16 + l16) * 40 + quad * 8];
      s16x8 vl = *(const s16x8*)&Vtl[(nt * 16 + l16) * 40 + quad * 8];
      o_acc[nt] = __builtin_amdgcn_mfma_f32_16x16x32_bf16(pfh, vh, o_acc[nt], 0, 0, 0);
      o_acc[nt] = __builtin_amdgcn_mfma_f32_16x16x32_bf16(pfh, vl, o_acc[nt], 0, 0, 0);
      o_acc[nt] = __builtin_amdgcn_mfma_f32_16x16x32_bf16(pfl, vh, o_acc[nt], 0, 0, 0);
    }
  }
#pragma unroll
  for (int r = 0; r < 4; r++) {
    int trow = tb + qt * 64 + wv * 16 + quad * 4 + r;
    float inv_l = 1.f / l_i[r];
    float* op = O + (size_t)trow * 2048 + h * 128;
#pragma unroll
    for (int nt = 0; nt < 8; nt++) op[nt * 16 + l16] = o_acc[nt][r] * inv_l;
  }
}

// ---------------- host ----------------
extern "C" void kernel_launch(void* const* d_in, const int* in_sizes, int n_in,
                              void* d_out, int out_size, void* d_ws, size_t ws_size,
                              hipStream_t stream) {
  const float* x = (const float*)d_in[0];
  const float* fcos = (const float*)d_in[1];
  const float* fsin = (const float*)d_in[2];
  const float* attn_w = (const float*)d_in[3];
  const float* wq = (const float*)d_in[4];
  const float* wkva = (const float*)d_in[5];
  const float* kvnw = (const float*)d_in[6];
  const float* wkvb = (const float*)d_in[7];
  const float* wo = (const float*)d_in[8];
  const float* ffnw = (const float*)d_in[9];
  const float* rw = (const float*)d_in[10];
  const float* ew1 = (const float*)d_in[11];
  const float* ew3 = (const float*)d_in[12];
  const float* ew2 = (const float*)d_in[13];
  const float* sw1 = (const float*)d_in[14];
  const float* sw3 = (const float*)d_in[15];
  const float* sw2 = (const float*)d_in[16];
  float* out = (float*)d_out;

  char* ws = (char*)d_ws;
  size_t off = 0;
  auto alloc = [&](size_t bytes) -> char* {
    char* p = ws + off;
    off += (bytes + 255) & ~(size_t)255;
    return p;
  };
  // ---- persistent ----
  u16* wq_h = (u16*)alloc((size_t)3072 * 2048 * 2);
  u16* wq_l = (u16*)alloc((size_t)3072 * 2048 * 2);
  u16* wkva_h = (u16*)alloc((size_t)640 * 2048 * 2);
  u16* wkva_l = (u16*)alloc((size_t)640 * 2048 * 2);
  u16* wkvb_h = (u16*)alloc((size_t)4096 * 512 * 2);
  u16* wkvb_l = (u16*)alloc((size_t)4096 * 512 * 2);
  u16* wo_h = (u16*)alloc((size_t)2048 * 2048 * 2);
  u16* wo_l = (u16*)alloc((size_t)2048 * 2048 * 2);
  u16* sw1_b = (u16*)alloc((size_t)2816 * 2048 * 2);
  u16* sw3_b = (u16*)alloc((size_t)2816 * 2048 * 2);
  u16* sw2_b = (u16*)alloc((size_t)2048 * 2816 * 2);
  float* h_f = (float*)alloc((size_t)TT * 2048 * 4);
  u16* nh_b = (u16*)alloc((size_t)TT * 2048 * 2);
  float* gates_f = (float*)alloc((size_t)TT * 8 * 4);
  u16* attn_h = (u16*)alloc((size_t)TT * 2048 * 2);
  u16* attn_l = (u16*)alloc((size_t)TT * 2048 * 2);
  // ---- arena (phase A = attention, phase B = FFN overlap) ----
  size_t arena0 = off;
  u16* nx_h = (u16*)alloc((size_t)TT * 2048 * 2);
  u16* nx_l = (u16*)alloc((size_t)TT * 2048 * 2);
  float* R1 = (float*)alloc((size_t)TT * 4096 * 4);  // q_f(3072) / kvb_f(4096) / attn_f(2048)
  u16* q_h = (u16*)alloc((size_t)TT * 3072 * 2);
  u16* q_l = (u16*)alloc((size_t)TT * 3072 * 2);
  float* kv_f = (float*)alloc((size_t)TT * 640 * 4);
  u16* ckv_h = (u16*)alloc((size_t)TT * 512 * 2);
  u16* ckv_l = (u16*)alloc((size_t)TT * 512 * 2);
  u16* kpe_h = (u16*)alloc((size_t)TT * 64 * 2);
  u16* kpe_l = (u16*)alloc((size_t)TT * 64 * 2);
  u16* kvb_h = (u16*)alloc((size_t)TT * 4096 * 2);
  u16* kvb_l = (u16*)alloc((size_t)TT * 4096 * 2);
  size_t total = off;
  // phase B aliases into the arena
  {
    size_t o2 = arena0;
    auto alloc2 = [&](size_t bytes) -> char* {
      char* p = ws + o2;
      o2 += (bytes + 255) & ~(size_t)255;
      return p;
    };
    (void)alloc2;
    // assigned below
  }
  size_t o2 = arena0;
  auto alloc2 = [&](size_t bytes) -> char* {
    char* p = ws + o2;
    o2 += (bytes + 255) & ~(size_t)255;
    return p;
  };
  u16* ew1_t = (u16*)alloc2((size_t)MINTER * 2048 * 2);
  u16* ew3_t = (u16*)alloc2((size_t)MINTER * 2048 * 2);
  u16* ew2_t = (u16*)alloc2((size_t)2048 * MINTER * 2);
  u16* g1_b = (u16*)alloc2((size_t)TT * SHI * 2);
  u16* g3_b = (u16*)alloc2((size_t)TT * SHI * 2);
  u16* h1_b = (u16*)alloc2((size_t)TT * SHI * 2);
  if (ws_size < total) return;  // insufficient scratch -> zero output, fail loud

  float* q_f = R1;     // TT x 3072
  float* kvb_f = R1;   // TT x 4096 (after q split)
  float* attn_f = R1;  // TT x 2048 (after kvb split)

  // ---- weight converts ----
  split_f32<<<(3072 * 2048) / 256, 256, 0, stream>>>(wq, wq_h, wq_l, 3072 * 2048);
  split_wkva<<<(640 * 2048) / 256, 256, 0, stream>>>(wkva, wkva_h, wkva_l);
  split_f32<<<(4096 * 512) / 256, 256, 0, stream>>>(wkvb, wkvb_h, wkvb_l, 4096 * 512);
  split_f32<<<(2048 * 2048) / 256, 256, 0, stream>>>(wo, wo_h, wo_l, 2048 * 2048);
  cvt3_bf16<<<(2816 * 2048) / 256, 256, 0, stream>>>(sw1, sw3, sw2, sw1_b, sw3_b, sw2_b, 2816 * 2048);

  // ---- attention path (split-bf16, f32-grade) ----
  rmsnorm_split<<<TT, 256, 0, stream>>>(x, attn_w, nx_h, nx_l);
  // q = nx @ wq^T  (3-pass split)
  gemm_bt<EPI_F32><<<dim3(24, 32), 256, 0, stream>>>(nx_h, wq_h, q_f, nullptr, TT, 3072, 2048);
  gemm_bt<EPI_ADD><<<dim3(24, 32), 256, 0, stream>>>(nx_h, wq_l, q_f, nullptr, TT, 3072, 2048);
  gemm_bt<EPI_ADD><<<dim3(24, 32), 256, 0, stream>>>(nx_l, wq_h, q_f, nullptr, TT, 3072, 2048);
  rope_qf<<<(TT * NH * 32) / 256, 256, 0, stream>>>(q_f, fcos, fsin);
  split_f32<<<(TT * 3072) / 256, 256, 0, stream>>>(q_f, q_h, q_l, TT * 3072);
  // kv = nx @ wkv_a^T (padded to 640)
  gemm_bt<EPI_F32><<<dim3(5, 32), 256, 0, stream>>>(nx_h, wkva_h, kv_f, nullptr, TT, 640, 2048);
  gemm_bt<EPI_ADD><<<dim3(5, 32), 256, 0, stream>>>(nx_h, wkva_l, kv_f, nullptr, TT, 640, 2048);
  gemm_bt<EPI_ADD><<<dim3(5, 32), 256, 0, stream>>>(nx_l, wkva_h, kv_f, nullptr, TT, 640, 2048);
  kv_norm_rope_split<<<TT, 256, 0, stream>>>(kv_f, kvnw, fcos, fsin, ckv_h, ckv_l, kpe_h, kpe_l);
  // kvb = ckv @ wkv_b^T
  gemm_bt<EPI_F32><<<dim3(32, 32), 256, 0, stream>>>(ckv_h, wkvb_h, kvb_f, nullptr, TT, 4096, 512);
  gemm_bt<EPI_ADD><<<dim3(32, 32), 256, 0, stream>>>(ckv_h, wkvb_l, kvb_f, nullptr, TT, 4096, 512);
  gemm_bt<EPI_ADD><<<dim3(32, 32), 256, 0, stream>>>(ckv_l, wkvb_h, kvb_f, nullptr, TT, 4096, 512);
  split_f32<<<(TT * 4096) / 256, 256, 0, stream>>>(kvb_f, kvb_h, kvb_l, TT * 4096);
  // flash attention -> f32 attn
  flash_attn_split<<<dim3(SS / 64, BB * NH), 256, 0, stream>>>(q_h, q_l, kvb_h, kvb_l,
                                                               kpe_h, kpe_l, attn_f);
  split_f32<<<(TT * 2048) / 256, 256, 0, stream>>>(attn_f, attn_h, attn_l, TT * 2048);
  // h = x + attn @ wo^T
  gemm_bt<EPI_F32><<<dim3(16, 32), 256, 0, stream>>>(attn_h, wo_h, h_f, nullptr, TT, 2048, 2048);
  gemm_bt<EPI_ADD><<<dim3(16, 32), 256, 0, stream>>>(attn_h, wo_l, h_f, nullptr, TT, 2048, 2048);
  gemm_bt<EPI_ADD><<<dim3(16, 32), 256, 0, stream>>>(attn_l, wo_h, h_f, nullptr, TT, 2048, 2048);
  add_residual<<<(TT * 2048) / 256, 256, 0, stream>>>(h_f, x, out, TT * 2048);

  // ---- FFN path ----
  rmsnorm_bf16<<<TT, 256, 0, stream>>>(h_f, ffnw, nh_b);
  router_f32<<<TT, 256, 0, stream>>>(h_f, ffnw, rw, gates_f);
  // shared expert (plain bf16)
  gemm_bt<EPI_BF16><<<dim3(22, 32), 256, 0, stream>>>(nh_b, sw1_b, g1_b, nullptr, TT, SHI, 2048);
  gemm_bt<EPI_BF16><<<dim3(22, 32), 256, 0, stream>>>(nh_b, sw3_b, g3_b, nullptr, TT, SHI, 2048);
  silu_mul<<<(TT * SHI) / 256, 256, 0, stream>>>(g1_b, g3_b, h1_b, TT * SHI);
  gemm_bt<EPI_ADD><<<dim3(16, 32), 256, 0, stream>>>(h1_b, sw2_b, out, nullptr, TT, 2048, SHI);
  // dense MoE (gates zero-mask unselected experts)
  for (int e = 0; e < NE; e++) {
    const float* w1p = ew1 + (size_t)e * MINTER * 2048;
    const float* w3p = ew3 + (size_t)e * MINTER * 2048;
    const float* w2p = ew2 + (size_t)e * 2048 * MINTER;
    cvt3_bf16<<<(MINTER * 2048) / 256, 256, 0, stream>>>(w1p, w3p, w2p, ew1_t, ew3_t, ew2_t, MINTER * 2048);
    gemm_bt<EPI_BF16><<<dim3(11, 32), 256, 0, stream>>>(nh_b, ew1_t, g1_b, nullptr, TT, MINTER, 2048);
    gemm_bt<EPI_BF16><<<dim3(11, 32), 256, 0, stream>>>(nh_b, ew3_t, g3_b, nullptr, TT, MINTER, 2048);
    silu_mul<<<(TT * MINTER) / 256, 256, 0, stream>>>(g1_b, g3_b, h1_b, TT * MINTER);
    gemm_bt<EPI_ADD_GATED><<<dim3(16, 32), 256, 0, stream>>>(h1_b, ew2_t, out, gates_f + e, TT, 2048, MINTER);
  }
}